// Round 21
// baseline (306.400 us; speedup 1.0000x reference)
//
#include <hip/hip_runtime.h>
#include <hip/hip_bf16.h>
#include <cstdint>

// ---------------------------------------------------------------------------
// LSTM cell fused forward on MI355X (gfx950).
//   gates = [input|hidden] @ [W;U] + b  -- single-product fp16 emulation
//   gate GEMM: R18-proven 128^2 tile, 4 waves (64x64), BK=64 (2 x BK32
//              subtiles), 32KB LDS, zero-conflict 64B-row swizzle, XCD
//              n-chunk block swizzle.  Fused LSTM epilogue uses DPP
//              quad-broadcast (VALU) instead of __shfl (ds_bpermute/LDS port).
//   logits = h_hi @ W_h + b_h (1-product); log_softmax row-wise (hw exp/log).
// ---------------------------------------------------------------------------

#define B_DIM   8192
#define K1      2048
#define H_DIM   1024

typedef __attribute__((ext_vector_type(8))) _Float16 f16x8;
typedef __attribute__((ext_vector_type(4))) float    f32x4;

__device__ __forceinline__ unsigned short f2h_bits(float x) {
    _Float16 h = (_Float16)x;
    return __builtin_bit_cast(unsigned short, h);
}

__device__ __forceinline__ void gload_lds16(const void* g, void* l) {
    __builtin_amdgcn_global_load_lds(
        (const __attribute__((address_space(1))) void*)g,
        (__attribute__((address_space(3))) void*)l, 16, 0, 0);
}

__device__ __forceinline__ f32x4 mfma16(f16x8 a, f16x8 b, f32x4 c) {
    return __builtin_amdgcn_mfma_f32_16x16x32_f16(a, b, c, 0, 0, 0);
}

// raw hardware exp2 / log2 / rcp (saturation-correct; ~1 ulp)
__device__ __forceinline__ float vexp2(float x) {
    float r; asm("v_exp_f32 %0, %1" : "=v"(r) : "v"(x)); return r;
}
__device__ __forceinline__ float vlog2(float x) {
    float r; asm("v_log_f32 %0, %1" : "=v"(r) : "v"(x)); return r;
}
__device__ __forceinline__ float vrcp(float x) {
    float r; asm("v_rcp_f32 %0, %1" : "=v"(r) : "v"(x)); return r;
}
__device__ __forceinline__ float fast_sigmoid(float v) {
    return vrcp(1.0f + vexp2(-1.44269504f * v));
}
__device__ __forceinline__ float fast_tanh(float v) {
    return 1.0f - 2.0f * vrcp(1.0f + vexp2(2.88539008f * v));
}

// quad-broadcast via DPP quad_perm[g,g,g,g] -- VALU, no LDS port.
template <int CTRL>
__device__ __forceinline__ float quad_bcast(float x) {
    return __int_as_float(__builtin_amdgcn_mov_dpp(
        __float_as_int(x), CTRL, 0xF, 0xF, true));
}

// ---------------------------------------------------------------------------
// Pack X = [input | hidden] (row-major [8192][2048]) into fp16.
// ---------------------------------------------------------------------------
__global__ __launch_bounds__(256) void k_split_x(
    const float* __restrict__ input, const float* __restrict__ hidden,
    unsigned short* __restrict__ xhi) {
    const int64_t n4 = (int64_t)B_DIM * K1 / 4;
    for (int64_t i = (int64_t)blockIdx.x * blockDim.x + threadIdx.x; i < n4;
         i += (int64_t)gridDim.x * blockDim.x) {
        int64_t e = i * 4;
        int row = (int)(e >> 11);
        int col = (int)(e & 2047);
        const float* src = (col < 1024) ? (input + (int64_t)row * 1024 + col)
                                        : (hidden + (int64_t)row * 1024 + (col - 1024));
        float4 v = *(const float4*)src;
        ushort4 hv;
        hv.x = f2h_bits(v.x);
        hv.y = f2h_bits(v.y);
        hv.z = f2h_bits(v.z);
        hv.w = f2h_bits(v.w);
        *(ushort4*)(xhi + e) = hv;
    }
}

// ---------------------------------------------------------------------------
// Fused transpose of all 8 gate weights into wuhi[n'=4h+g][k] fp16.
// blockIdx.z: 0-3 = W_{f,i,c,o} (koff 0), 4-7 = U_{f,i,c,o} (koff 1024).
// ---------------------------------------------------------------------------
__global__ __launch_bounds__(256) void k_trans_all(
    const float* __restrict__ W_f, const float* __restrict__ W_i,
    const float* __restrict__ W_c, const float* __restrict__ W_o,
    const float* __restrict__ U_f, const float* __restrict__ U_i,
    const float* __restrict__ U_c, const float* __restrict__ U_o,
    unsigned short* __restrict__ wuhi) {
    const int z = blockIdx.z;
    const float* src;
    if      (z == 0) src = W_f;
    else if (z == 1) src = W_i;
    else if (z == 2) src = W_c;
    else if (z == 3) src = W_o;
    else if (z == 4) src = U_f;
    else if (z == 5) src = U_i;
    else if (z == 6) src = U_c;
    else             src = U_o;
    const int ng = z & 3, koff = (z >> 2) * 1024;

    __shared__ float t[64][65];
    const int h0 = blockIdx.x * 64;
    const int k0 = blockIdx.y * 64;
    const int tx = threadIdx.x & 63, ty = threadIdx.x >> 6;
    #pragma unroll
    for (int r = ty; r < 64; r += 4)
        t[r][tx] = src[(int64_t)(k0 + r) * 1024 + h0 + tx];
    __syncthreads();
    #pragma unroll
    for (int r = ty; r < 64; r += 4) {
        float v = t[tx][r];
        int np = (h0 + r) * 4 + ng;
        wuhi[(int64_t)np * 2048 + koff + k0 + tx] = f2h_bits(v);
    }
}

// W_h [1024x1024] (k-major) -> whh[n][k] fp16.
__global__ __launch_bounds__(256) void k_trans_wh(
    const float* __restrict__ src, unsigned short* __restrict__ whh) {
    __shared__ float t[64][65];
    const int h0 = blockIdx.x * 64;
    const int k0 = blockIdx.y * 64;
    const int tx = threadIdx.x & 63, ty = threadIdx.x >> 6;
    #pragma unroll
    for (int r = ty; r < 64; r += 4)
        t[r][tx] = src[(int64_t)(k0 + r) * 1024 + h0 + tx];
    __syncthreads();
    #pragma unroll
    for (int r = ty; r < 64; r += 4)
        whh[(int64_t)(h0 + r) * 1024 + k0 + tx] = f2h_bits(t[tx][r]);
}

// bias4[n'] = b_g[h], n' = 4h+g
__global__ __launch_bounds__(256) void k_pack_bias(
    const float* __restrict__ bf_, const float* __restrict__ bi_,
    const float* __restrict__ bc_, const float* __restrict__ bo_,
    float* __restrict__ bias4) {
    int n = blockIdx.x * 256 + threadIdx.x;
    if (n < 4096) {
        int g = n & 3, h = n >> 2;
        const float* p = (g == 0) ? bf_ : (g == 1) ? bi_ : (g == 2) ? bc_ : bo_;
        bias4[n] = p[h];
    }
}

// ---------------------------------------------------------------------------
// GATE GEMM: single-product fp16, R18 geometry + XCD n-chunk swizzle.
// 128x128 tile, BK=64 as two BK32 subtiles, 4 waves (2M x 2N, 64x64 each),
// 16x16x32 MFMA, 32KB LDS.  Subtile LDS (16KB): A rows 64B + B rows 64B,
// slot = q ^ ((row>>1)&3) (proven 0 conflicts).  Loop (32 iters):
// {sync; 8 gload_lds; sync; sub0 8 reads+16 MFMA; sub1 8 reads+16 MFMA}.
// Fused LSTM epilogue: DPP quad-broadcast (VALU) replaces __shfl
// (ds_bpermute = LDS-port op; 256/thread was ~41us of port time).
// ---------------------------------------------------------------------------
__global__ __launch_bounds__(256, 2) void k_gate_gemm(
    const char* __restrict__ Ah, const char* __restrict__ Bh,
    const float* __restrict__ bias,
    const float* __restrict__ cell,
    float* __restrict__ out0,
    _Float16* __restrict__ hhi) {
    __shared__ char smem[32768];  // 2 subtiles x (A 8KB | B 8KB)

    const int tid  = threadIdx.x;
    const int lane = tid & 63;
    const int w    = tid >> 6;           // wave 0..3
    const int wr   = (w >> 1) * 64;      // wave M offset
    const int wc   = (w & 1) * 64;       // wave N offset
    const int fr   = lane & 15;
    const int q    = lane >> 4;

    // XCD n-chunk swizzle (bijective: lin <-> (xcd, wi&3, wi>>2))
    const int lin = blockIdx.y * 32 + blockIdx.x;   // grid dim3(32,64)
    const int xcd = lin & 7;
    const int wi  = lin >> 3;            // 0..255
    const int n_blk = xcd * 4 + (wi & 3);
    const int m_blk = wi >> 2;
    const int m0 = m_blk * 128;
    const int n0 = n_blk * 128;

    f32x4 acc[4][4];
    #pragma unroll
    for (int i = 0; i < 4; i++)
        #pragma unroll
        for (int j = 0; j < 4; j++) acc[i][j] = (f32x4){0.f, 0.f, 0.f, 0.f};

    // --- staging sources (global side carries the swizzle; linear LDS dest) ---
    const int srow = tid >> 2;             // row within 64-row chunk (0..63)
    const int sg   = (tid & 3) ^ ((tid >> 3) & 3);  // logical k-chunk
    const char* As = Ah + (int64_t)(m0 + srow) * 4096 + sg * 16;
    const char* Bs = Bh + (int64_t)(n0 + srow) * 4096 + sg * 16;

    // --- ds_read side swizzle (64B rows) ---
    const unsigned slot = (unsigned)((q ^ ((fr >> 1) & 3)) << 4);

    for (int t = 0; t < 32; ++t) {       // 64-K per iteration
        __syncthreads();   // previous-iteration LDS readers done
        #pragma unroll
        for (int s = 0; s < 2; ++s) {
            const int kk = 2 * t + s;    // 32-K step index
            #pragma unroll
            for (int i = 0; i < 2; i++)
                gload_lds16(As + (int64_t)i * 64 * 4096 + kk * 64,
                            smem + s * 16384 + i * 4096 + tid * 16);
            #pragma unroll
            for (int i = 0; i < 2; i++)
                gload_lds16(Bs + (int64_t)i * 64 * 4096 + kk * 64,
                            smem + s * 16384 + 8192 + i * 4096 + tid * 16);
        }
        __syncthreads();   // loads landed (one vmcnt drain per 64-K)

        #pragma unroll
        for (int s = 0; s < 2; ++s) {
            const char* sA = smem + s * 16384;
            const char* sB = sA + 8192;
            f16x8 ah[4], bh[4];
            #pragma unroll
            for (int mi = 0; mi < 4; mi++)
                ah[mi] = *(const f16x8*)(sA + (wr + mi * 16 + fr) * 64 + slot);
            #pragma unroll
            for (int ni = 0; ni < 4; ni++)
                bh[ni] = *(const f16x8*)(sB + (wc + ni * 16 + fr) * 64 + slot);

            #pragma unroll
            for (int ni = 0; ni < 4; ni++)
                #pragma unroll
                for (int mi = 0; mi < 4; mi++)
                    acc[mi][ni] = mfma16(ah[mi], bh[ni], acc[mi][ni]);
        }
    }

    // ---- fused LSTM epilogue (16x16 C layout: col=lane&15, row=q*4+j) ----
    const int64_t OFF_H = (int64_t)B_DIM * H_DIM;
    const int64_t OFF_C = (int64_t)2 * B_DIM * H_DIM;
    const int g = lane & 3;
    #pragma unroll
    for (int mi = 0; mi < 4; mi++)
        #pragma unroll
        for (int ni = 0; ni < 4; ni++) {
            int col = n0 + wc + ni * 16 + fr;  // n' = 4h+g
            int h = col >> 2;
            float bb = bias[col];
            int rowb = m0 + wr + mi * 16 + q * 4;
            #pragma unroll
            for (int j = 0; j < 4; j++) {
                float v = acc[mi][ni][j] + bb;
                float a = (g == 2) ? fast_tanh(v) : fast_sigmoid(v);
                // quad lanes 4h..4h+3 hold gates f,i,c,o of the same h:
                // broadcast within quad via DPP (VALU; no LDS port).
                float fg = quad_bcast<0x00>(a);
                float ig = quad_bcast<0x55>(a);
                float ct = quad_bcast<0xAA>(a);
                float og = quad_bcast<0xFF>(a);
                int row = rowb + j;
                int64_t o = (int64_t)row * H_DIM + h;
                float cn = fg * cell[o] + ig * ct;
                float hn = og * fast_tanh(cn);
                if (g == 0) {
                    out0[OFF_C + o] = cn;
                } else if (g == 1) {
                    out0[OFF_H + o] = hn;
                } else if (g == 2) {
                    hhi[o] = (_Float16)hn;
                }
            }
        }
}

// ---------------------------------------------------------------------------
// LOGITS GEMM: fp16 single-product, 128x128 tile, BK=32, 4 waves.
// A = h_hi fp16 [8192][1024]; B = W_h^T fp16 [1024][1024].  64B-row layout,
// slot = q ^ ((row>>1)&3).
// ---------------------------------------------------------------------------
__global__ __launch_bounds__(256, 2) void k_gemm128(
    const char* __restrict__ Ah, const char* __restrict__ Bh,
    const float* __restrict__ bias,
    float* __restrict__ out0) {
    __shared__ char smem[16384];  // A 8KB | B 8KB

    const int tid  = threadIdx.x;
    const int lane = tid & 63;
    const int w    = tid >> 6;
    const int wr   = (w >> 1) * 64;
    const int wc   = (w & 1) * 64;
    const int m0   = blockIdx.y * 128;
    const int n0   = blockIdx.x * 128;
    const int fr   = lane & 15;
    const int q    = lane >> 4;

    f32x4 acc[4][4];
    #pragma unroll
    for (int i = 0; i < 4; i++)
        #pragma unroll
        for (int j = 0; j < 4; j++) acc[i][j] = (f32x4){0.f, 0.f, 0.f, 0.f};

    const int srow = tid >> 2;             // row within 64-row chunk (0..63)
    const int sg   = (tid & 3) ^ ((tid >> 3) & 3);  // logical k-chunk
    const char* Asrc = Ah + (int64_t)(m0 + srow) * 2048 + sg * 16;
    const char* Bsrc = Bh + (int64_t)(n0 + srow) * 2048 + sg * 16;

    const unsigned slot = (unsigned)((q ^ ((fr >> 1) & 3)) << 4);

    for (int t = 0; t < 32; ++t) {   // K=1024, BK=32
        __syncthreads();
        #pragma unroll
        for (int i = 0; i < 2; i++)
            gload_lds16(Asrc + (int64_t)i * 64 * 2048 + t * 64,
                        smem + i * 4096 + tid * 16);
        #pragma unroll
        for (int i = 0; i < 2; i++)
            gload_lds16(Bsrc + (int64_t)i * 64 * 2048 + t * 64,
                        smem + 8192 + i * 4096 + tid * 16);
        __syncthreads();

        f16x8 ah[4], bh[4];
        #pragma unroll
        for (int mi = 0; mi < 4; mi++)
            ah[mi] = *(const f16x8*)(smem + (wr + mi * 16 + fr) * 64 + slot);
        #pragma unroll
        for (int ni = 0; ni < 4; ni++)
            bh[ni] = *(const f16x8*)(smem + 8192 + (wc + ni * 16 + fr) * 64 + slot);

        #pragma unroll
        for (int ni = 0; ni < 4; ni++)
            #pragma unroll
            for (int mi = 0; mi < 4; mi++)
                acc[mi][ni] = mfma16(ah[mi], bh[ni], acc[mi][ni]);
    }

    #pragma unroll
    for (int mi = 0; mi < 4; mi++)
        #pragma unroll
        for (int ni = 0; ni < 4; ni++) {
            int col = n0 + wc + ni * 16 + fr;
            int rowb = m0 + wr + mi * 16 + q * 4;
            float bb = bias[col];
            #pragma unroll
            for (int j = 0; j < 4; j++)
                out0[(int64_t)(rowb + j) * 1024 + col] = acc[mi][ni][j] + bb;
        }
}

// ---------------------------------------------------------------------------
// Row-wise log_softmax over [8192][1024]: one block per row (hw exp2/log2).
// ---------------------------------------------------------------------------
__global__ __launch_bounds__(256) void k_logsoftmax(
    const float* __restrict__ logits, float* __restrict__ out) {
    const int row = blockIdx.x;
    const int t = threadIdx.x;
    const float* x = logits + (int64_t)row * 1024;
    float4 v = *(const float4*)(x + t * 4);

    float m = fmaxf(fmaxf(v.x, v.y), fmaxf(v.z, v.w));
    #pragma unroll
    for (int off = 1; off < 64; off <<= 1) m = fmaxf(m, __shfl_xor(m, off, 64));
    __shared__ float sm[4];
    __shared__ float ssum[4];
    int ln = t & 63, wv = t >> 6;
    if (ln == 0) sm[wv] = m;
    __syncthreads();
    m = fmaxf(fmaxf(sm[0], sm[1]), fmaxf(sm[2], sm[3]));

    const float L2E = 1.44269504f;
    float s = vexp2((v.x - m) * L2E) + vexp2((v.y - m) * L2E)
            + vexp2((v.z - m) * L2E) + vexp2((v.w - m) * L2E);
    #pragma unroll
    for (int off = 1; off < 64; off <<= 1) s += __shfl_xor(s, off, 64);
    if (ln == 0) ssum[wv] = s;
    __syncthreads();
    s = ssum[0] + ssum[1] + ssum[2] + ssum[3];

    float lse = m + vlog2(s) * 0.69314718f;
    float4 o;
    o.x = v.x - lse; o.y = v.y - lse; o.z = v.z - lse; o.w = v.w - lse;
    *(float4*)(out + (int64_t)row * 1024 + t * 4) = o;
}

// ---------------------------------------------------------------------------
extern "C" void kernel_launch(void* const* d_in, const int* in_sizes, int n_in,
                              void* d_out, int out_size, void* d_ws, size_t ws_size,
                              hipStream_t stream) {
    const float* input  = (const float*)d_in[0];
    const float* hidden = (const float*)d_in[1];
    const float* cell   = (const float*)d_in[2];
    const float* W_f = (const float*)d_in[3];
    const float* U_f = (const float*)d_in[4];
    const float* b_f = (const float*)d_in[5];
    const float* W_i = (const float*)d_in[6];
    const float* U_i = (const float*)d_in[7];
    const float* b_i = (const float*)d_in[8];
    const float* W_c = (const float*)d_in[9];
    const float* U_c = (const float*)d_in[10];
    const float* b_c = (const float*)d_in[11];
    const float* W_o = (const float*)d_in[12];
    const float* U_o = (const float*)d_in[13];
    const float* b_o = (const float*)d_in[14];
    const float* W_h = (const float*)d_in[15];
    const float* b_h = (const float*)d_in[16];
    float* out = (float*)d_out;

    char* ws = (char*)d_ws;
    unsigned short* xhi  = (unsigned short*)(ws);               // 32 MB
    unsigned short* wuhi = (unsigned short*)(ws + 67108864);    // 16 MB
    _Float16*       hhi  = (_Float16*)(ws + 83886080);          // 16 MB
    unsigned short* whh  = (unsigned short*)(ws + 117440512);   // 2 MB
    float*          bias4 = (float*)(ws + 119537664);           // 16 KB
    float*          logits = (float*)(ws + 33554432);           // 32 MB (free region)
    if (ws_size < (size_t)119554048) return;

    k_split_x<<<2048, 256, 0, stream>>>(input, hidden, xhi);
    k_trans_all<<<dim3(16, 16, 8), 256, 0, stream>>>(
        W_f, W_i, W_c, W_o, U_f, U_i, U_c, U_o, wuhi);
    k_trans_wh<<<dim3(16, 16), 256, 0, stream>>>(W_h, whh);
    k_pack_bias<<<16, 256, 0, stream>>>(b_f, b_i, b_c, b_o, bias4);

    // gates GEMM + fused LSTM epilogue: M=8192, N'=4096, K=2048, 2048 blocks
    k_gate_gemm<<<dim3(32, 64), 256, 0, stream>>>(
        (const char*)xhi, (const char*)wuhi, bias4, cell, out, hhi);

    // logits GEMM: M=8192, N=1024, K=1024 (single-product)
    k_gemm128<<<dim3(8, 64), 256, 0, stream>>>(
        (const char*)hhi, (const char*)whh, b_h, logits);

    k_logsoftmax<<<8192, 256, 0, stream>>>(logits, out);
}

// Round 22
// 300.124 us; speedup vs baseline: 1.0209x; 1.0209x over previous
//
#include <hip/hip_runtime.h>
#include <hip/hip_bf16.h>
#include <cstdint>

// ---------------------------------------------------------------------------
// LSTM cell fused forward on MI355X (gfx950).  FINAL (R20 best: 300.3us).
//   gates = [input|hidden] @ [W;U] + b  -- single-product fp16 emulation
//   gate GEMM: 128^2 tile, 4 waves (64x64), BK=64 (2 x BK32 subtiles),
//              32KB LDS, zero-conflict 64B-row swizzle, XCD n-chunk swizzle
//   elementwise LSTM epilogue fused (fast v_exp/v_rcp transcendentals);
//   logits = h_hi @ W_h + b_h (1-product); log_softmax row-wise (hw exp/log).
// ---------------------------------------------------------------------------

#define B_DIM   8192
#define K1      2048
#define H_DIM   1024

typedef __attribute__((ext_vector_type(8))) _Float16 f16x8;
typedef __attribute__((ext_vector_type(4))) float    f32x4;

__device__ __forceinline__ unsigned short f2h_bits(float x) {
    _Float16 h = (_Float16)x;
    return __builtin_bit_cast(unsigned short, h);
}

__device__ __forceinline__ void gload_lds16(const void* g, void* l) {
    __builtin_amdgcn_global_load_lds(
        (const __attribute__((address_space(1))) void*)g,
        (__attribute__((address_space(3))) void*)l, 16, 0, 0);
}

__device__ __forceinline__ f32x4 mfma16(f16x8 a, f16x8 b, f32x4 c) {
    return __builtin_amdgcn_mfma_f32_16x16x32_f16(a, b, c, 0, 0, 0);
}

// raw hardware exp2 / log2 / rcp (saturation-correct; ~1 ulp)
__device__ __forceinline__ float vexp2(float x) {
    float r; asm("v_exp_f32 %0, %1" : "=v"(r) : "v"(x)); return r;
}
__device__ __forceinline__ float vlog2(float x) {
    float r; asm("v_log_f32 %0, %1" : "=v"(r) : "v"(x)); return r;
}
__device__ __forceinline__ float vrcp(float x) {
    float r; asm("v_rcp_f32 %0, %1" : "=v"(r) : "v"(x)); return r;
}
__device__ __forceinline__ float fast_sigmoid(float v) {
    return vrcp(1.0f + vexp2(-1.44269504f * v));
}
__device__ __forceinline__ float fast_tanh(float v) {
    return 1.0f - 2.0f * vrcp(1.0f + vexp2(2.88539008f * v));
}

// ---------------------------------------------------------------------------
// Pack X = [input | hidden] (row-major [8192][2048]) into fp16.
// ---------------------------------------------------------------------------
__global__ __launch_bounds__(256) void k_split_x(
    const float* __restrict__ input, const float* __restrict__ hidden,
    unsigned short* __restrict__ xhi) {
    const int64_t n4 = (int64_t)B_DIM * K1 / 4;
    for (int64_t i = (int64_t)blockIdx.x * blockDim.x + threadIdx.x; i < n4;
         i += (int64_t)gridDim.x * blockDim.x) {
        int64_t e = i * 4;
        int row = (int)(e >> 11);
        int col = (int)(e & 2047);
        const float* src = (col < 1024) ? (input + (int64_t)row * 1024 + col)
                                        : (hidden + (int64_t)row * 1024 + (col - 1024));
        float4 v = *(const float4*)src;
        ushort4 hv;
        hv.x = f2h_bits(v.x);
        hv.y = f2h_bits(v.y);
        hv.z = f2h_bits(v.z);
        hv.w = f2h_bits(v.w);
        *(ushort4*)(xhi + e) = hv;
    }
}

// ---------------------------------------------------------------------------
// Fused transpose of all 8 gate weights into wuhi[n'=4h+g][k] fp16.
// blockIdx.z: 0-3 = W_{f,i,c,o} (koff 0), 4-7 = U_{f,i,c,o} (koff 1024).
// ---------------------------------------------------------------------------
__global__ __launch_bounds__(256) void k_trans_all(
    const float* __restrict__ W_f, const float* __restrict__ W_i,
    const float* __restrict__ W_c, const float* __restrict__ W_o,
    const float* __restrict__ U_f, const float* __restrict__ U_i,
    const float* __restrict__ U_c, const float* __restrict__ U_o,
    unsigned short* __restrict__ wuhi) {
    const int z = blockIdx.z;
    const float* src;
    if      (z == 0) src = W_f;
    else if (z == 1) src = W_i;
    else if (z == 2) src = W_c;
    else if (z == 3) src = W_o;
    else if (z == 4) src = U_f;
    else if (z == 5) src = U_i;
    else if (z == 6) src = U_c;
    else             src = U_o;
    const int ng = z & 3, koff = (z >> 2) * 1024;

    __shared__ float t[64][65];
    const int h0 = blockIdx.x * 64;
    const int k0 = blockIdx.y * 64;
    const int tx = threadIdx.x & 63, ty = threadIdx.x >> 6;
    #pragma unroll
    for (int r = ty; r < 64; r += 4)
        t[r][tx] = src[(int64_t)(k0 + r) * 1024 + h0 + tx];
    __syncthreads();
    #pragma unroll
    for (int r = ty; r < 64; r += 4) {
        float v = t[tx][r];
        int np = (h0 + r) * 4 + ng;
        wuhi[(int64_t)np * 2048 + koff + k0 + tx] = f2h_bits(v);
    }
}

// W_h [1024x1024] (k-major) -> whh[n][k] fp16.
__global__ __launch_bounds__(256) void k_trans_wh(
    const float* __restrict__ src, unsigned short* __restrict__ whh) {
    __shared__ float t[64][65];
    const int h0 = blockIdx.x * 64;
    const int k0 = blockIdx.y * 64;
    const int tx = threadIdx.x & 63, ty = threadIdx.x >> 6;
    #pragma unroll
    for (int r = ty; r < 64; r += 4)
        t[r][tx] = src[(int64_t)(k0 + r) * 1024 + h0 + tx];
    __syncthreads();
    #pragma unroll
    for (int r = ty; r < 64; r += 4)
        whh[(int64_t)(h0 + r) * 1024 + k0 + tx] = f2h_bits(t[tx][r]);
}

// bias4[n'] = b_g[h], n' = 4h+g
__global__ __launch_bounds__(256) void k_pack_bias(
    const float* __restrict__ bf_, const float* __restrict__ bi_,
    const float* __restrict__ bc_, const float* __restrict__ bo_,
    float* __restrict__ bias4) {
    int n = blockIdx.x * 256 + threadIdx.x;
    if (n < 4096) {
        int g = n & 3, h = n >> 2;
        const float* p = (g == 0) ? bf_ : (g == 1) ? bi_ : (g == 2) ? bc_ : bo_;
        bias4[n] = p[h];
    }
}

// ---------------------------------------------------------------------------
// GATE GEMM: single-product fp16.  128x128 tile, BK=64 as two BK32 subtiles,
// 4 waves (2M x 2N, 64x64 each), 16x16x32 MFMA, 32KB LDS.  Subtile LDS
// (16KB): A rows 64B + B rows 64B, slot = q ^ ((row>>1)&3) (0 conflicts).
// Loop (32 iters): {sync; 8 gload_lds; sync; sub0 8 reads+16 MFMA;
// sub1 8 reads+16 MFMA} -- one vmcnt drain per 64-K.
// XCD n-chunk swizzle: xcd = lin%8 gets n-panels [4*xcd, 4*xcd+4).
// Fused LSTM epilogue (fast transcendentals).
// ---------------------------------------------------------------------------
__global__ __launch_bounds__(256, 2) void k_gate_gemm(
    const char* __restrict__ Ah, const char* __restrict__ Bh,
    const float* __restrict__ bias,
    const float* __restrict__ cell,
    float* __restrict__ out0,
    _Float16* __restrict__ hhi) {
    __shared__ char smem[32768];  // 2 subtiles x (A 8KB | B 8KB)

    const int tid  = threadIdx.x;
    const int lane = tid & 63;
    const int w    = tid >> 6;           // wave 0..3
    const int wr   = (w >> 1) * 64;      // wave M offset
    const int wc   = (w & 1) * 64;       // wave N offset
    const int fr   = lane & 15;
    const int q    = lane >> 4;

    // XCD n-chunk swizzle (bijective: lin <-> (xcd, wi&3, wi>>2))
    const int lin = blockIdx.y * 32 + blockIdx.x;   // grid dim3(32,64)
    const int xcd = lin & 7;
    const int wi  = lin >> 3;            // 0..255
    const int n_blk = xcd * 4 + (wi & 3);
    const int m_blk = wi >> 2;
    const int m0 = m_blk * 128;
    const int n0 = n_blk * 128;

    f32x4 acc[4][4];
    #pragma unroll
    for (int i = 0; i < 4; i++)
        #pragma unroll
        for (int j = 0; j < 4; j++) acc[i][j] = (f32x4){0.f, 0.f, 0.f, 0.f};

    // --- staging sources (global side carries the swizzle; linear LDS dest) ---
    const int srow = tid >> 2;             // row within 64-row chunk (0..63)
    const int sg   = (tid & 3) ^ ((tid >> 3) & 3);  // logical k-chunk
    const char* As = Ah + (int64_t)(m0 + srow) * 4096 + sg * 16;
    const char* Bs = Bh + (int64_t)(n0 + srow) * 4096 + sg * 16;

    // --- ds_read side swizzle (64B rows) ---
    const unsigned slot = (unsigned)((q ^ ((fr >> 1) & 3)) << 4);

    for (int t = 0; t < 32; ++t) {       // 64-K per iteration
        __syncthreads();   // previous-iteration LDS readers done
        #pragma unroll
        for (int s = 0; s < 2; ++s) {
            const int kk = 2 * t + s;    // 32-K step index
            #pragma unroll
            for (int i = 0; i < 2; i++)
                gload_lds16(As + (int64_t)i * 64 * 4096 + kk * 64,
                            smem + s * 16384 + i * 4096 + tid * 16);
            #pragma unroll
            for (int i = 0; i < 2; i++)
                gload_lds16(Bs + (int64_t)i * 64 * 4096 + kk * 64,
                            smem + s * 16384 + 8192 + i * 4096 + tid * 16);
        }
        __syncthreads();   // loads landed (one vmcnt drain per 64-K)

        #pragma unroll
        for (int s = 0; s < 2; ++s) {
            const char* sA = smem + s * 16384;
            const char* sB = sA + 8192;
            f16x8 ah[4], bh[4];
            #pragma unroll
            for (int mi = 0; mi < 4; mi++)
                ah[mi] = *(const f16x8*)(sA + (wr + mi * 16 + fr) * 64 + slot);
            #pragma unroll
            for (int ni = 0; ni < 4; ni++)
                bh[ni] = *(const f16x8*)(sB + (wc + ni * 16 + fr) * 64 + slot);

            #pragma unroll
            for (int ni = 0; ni < 4; ni++)
                #pragma unroll
                for (int mi = 0; mi < 4; mi++)
                    acc[mi][ni] = mfma16(ah[mi], bh[ni], acc[mi][ni]);
        }
    }

    // ---- fused LSTM epilogue (16x16 C layout: col=lane&15, row=q*4+j) ----
    const int lb = lane & ~3;  // quad lanes lb..lb+3 = gates f,i,c,o of one h
    const int64_t OFF_H = (int64_t)B_DIM * H_DIM;
    const int64_t OFF_C = (int64_t)2 * B_DIM * H_DIM;
    const int g = lane & 3;
    #pragma unroll
    for (int mi = 0; mi < 4; mi++)
        #pragma unroll
        for (int ni = 0; ni < 4; ni++) {
            int col = n0 + wc + ni * 16 + fr;  // n' = 4h+g
            int h = col >> 2;
            float bb = bias[col];
            int rowb = m0 + wr + mi * 16 + q * 4;
            #pragma unroll
            for (int j = 0; j < 4; j++) {
                float v = acc[mi][ni][j] + bb;
                float a = (g == 2) ? fast_tanh(v) : fast_sigmoid(v);
                float fg = __shfl(a, lb + 0, 64);
                float ig = __shfl(a, lb + 1, 64);
                float ct = __shfl(a, lb + 2, 64);
                float og = __shfl(a, lb + 3, 64);
                int row = rowb + j;
                int64_t o = (int64_t)row * H_DIM + h;
                float cn = fg * cell[o] + ig * ct;
                float hn = og * fast_tanh(cn);
                if (g == 0) {
                    out0[OFF_C + o] = cn;
                } else if (g == 1) {
                    out0[OFF_H + o] = hn;
                } else if (g == 2) {
                    hhi[o] = (_Float16)hn;
                }
            }
        }
}

// ---------------------------------------------------------------------------
// LOGITS GEMM: fp16 single-product, 128x128 tile, BK=32, 4 waves.
// A = h_hi fp16 [8192][1024]; B = W_h^T fp16 [1024][1024].  64B-row layout,
// slot = q ^ ((row>>1)&3).
// ---------------------------------------------------------------------------
__global__ __launch_bounds__(256, 2) void k_gemm128(
    const char* __restrict__ Ah, const char* __restrict__ Bh,
    const float* __restrict__ bias,
    float* __restrict__ out0) {
    __shared__ char smem[16384];  // A 8KB | B 8KB

    const int tid  = threadIdx.x;
    const int lane = tid & 63;
    const int w    = tid >> 6;
    const int wr   = (w >> 1) * 64;
    const int wc   = (w & 1) * 64;
    const int m0   = blockIdx.y * 128;
    const int n0   = blockIdx.x * 128;
    const int fr   = lane & 15;
    const int q    = lane >> 4;

    f32x4 acc[4][4];
    #pragma unroll
    for (int i = 0; i < 4; i++)
        #pragma unroll
        for (int j = 0; j < 4; j++) acc[i][j] = (f32x4){0.f, 0.f, 0.f, 0.f};

    const int srow = tid >> 2;             // row within 64-row chunk (0..63)
    const int sg   = (tid & 3) ^ ((tid >> 3) & 3);  // logical k-chunk
    const char* Asrc = Ah + (int64_t)(m0 + srow) * 2048 + sg * 16;
    const char* Bsrc = Bh + (int64_t)(n0 + srow) * 2048 + sg * 16;

    const unsigned slot = (unsigned)((q ^ ((fr >> 1) & 3)) << 4);

    for (int t = 0; t < 32; ++t) {   // K=1024, BK=32
        __syncthreads();
        #pragma unroll
        for (int i = 0; i < 2; i++)
            gload_lds16(Asrc + (int64_t)i * 64 * 2048 + t * 64,
                        smem + i * 4096 + tid * 16);
        #pragma unroll
        for (int i = 0; i < 2; i++)
            gload_lds16(Bsrc + (int64_t)i * 64 * 2048 + t * 64,
                        smem + 8192 + i * 4096 + tid * 16);
        __syncthreads();

        f16x8 ah[4], bh[4];
        #pragma unroll
        for (int mi = 0; mi < 4; mi++)
            ah[mi] = *(const f16x8*)(smem + (wr + mi * 16 + fr) * 64 + slot);
        #pragma unroll
        for (int ni = 0; ni < 4; ni++)
            bh[ni] = *(const f16x8*)(smem + 8192 + (wc + ni * 16 + fr) * 64 + slot);

        #pragma unroll
        for (int ni = 0; ni < 4; ni++)
            #pragma unroll
            for (int mi = 0; mi < 4; mi++)
                acc[mi][ni] = mfma16(ah[mi], bh[ni], acc[mi][ni]);
    }

    #pragma unroll
    for (int mi = 0; mi < 4; mi++)
        #pragma unroll
        for (int ni = 0; ni < 4; ni++) {
            int col = n0 + wc + ni * 16 + fr;
            int rowb = m0 + wr + mi * 16 + q * 4;
            float bb = bias[col];
            #pragma unroll
            for (int j = 0; j < 4; j++)
                out0[(int64_t)(rowb + j) * 1024 + col] = acc[mi][ni][j] + bb;
        }
}

// ---------------------------------------------------------------------------
// Row-wise log_softmax over [8192][1024]: one block per row (hw exp2/log2).
// ---------------------------------------------------------------------------
__global__ __launch_bounds__(256) void k_logsoftmax(
    const float* __restrict__ logits, float* __restrict__ out) {
    const int row = blockIdx.x;
    const int t = threadIdx.x;
    const float* x = logits + (int64_t)row * 1024;
    float4 v = *(const float4*)(x + t * 4);

    float m = fmaxf(fmaxf(v.x, v.y), fmaxf(v.z, v.w));
    #pragma unroll
    for (int off = 1; off < 64; off <<= 1) m = fmaxf(m, __shfl_xor(m, off, 64));
    __shared__ float sm[4];
    __shared__ float ssum[4];
    int ln = t & 63, wv = t >> 6;
    if (ln == 0) sm[wv] = m;
    __syncthreads();
    m = fmaxf(fmaxf(sm[0], sm[1]), fmaxf(sm[2], sm[3]));

    const float L2E = 1.44269504f;
    float s = vexp2((v.x - m) * L2E) + vexp2((v.y - m) * L2E)
            + vexp2((v.z - m) * L2E) + vexp2((v.w - m) * L2E);
    #pragma unroll
    for (int off = 1; off < 64; off <<= 1) s += __shfl_xor(s, off, 64);
    if (ln == 0) ssum[wv] = s;
    __syncthreads();
    s = ssum[0] + ssum[1] + ssum[2] + ssum[3];

    float lse = m + vlog2(s) * 0.69314718f;
    float4 o;
    o.x = v.x - lse; o.y = v.y - lse; o.z = v.z - lse; o.w = v.w - lse;
    *(float4*)(out + (int64_t)row * 1024 + t * 4) = o;
}

// ---------------------------------------------------------------------------
extern "C" void kernel_launch(void* const* d_in, const int* in_sizes, int n_in,
                              void* d_out, int out_size, void* d_ws, size_t ws_size,
                              hipStream_t stream) {
    const float* input  = (const float*)d_in[0];
    const float* hidden = (const float*)d_in[1];
    const float* cell   = (const float*)d_in[2];
    const float* W_f = (const float*)d_in[3];
    const float* U_f = (const float*)d_in[4];
    const float* b_f = (const float*)d_in[5];
    const float* W_i = (const float*)d_in[6];
    const float* U_i = (const float*)d_in[7];
    const float* b_i = (const float*)d_in[8];
    const float* W_c = (const float*)d_in[9];
    const float* U_c = (const float*)d_in[10];
    const float* b_c = (const float*)d_in[11];
    const float* W_o = (const float*)d_in[12];
    const float* U_o = (const float*)d_in[13];
    const float* b_o = (const float*)d_in[14];
    const float* W_h = (const float*)d_in[15];
    const float* b_h = (const float*)d_in[16];
    float* out = (float*)d_out;

    char* ws = (char*)d_ws;
    unsigned short* xhi  = (unsigned short*)(ws);               // 32 MB
    unsigned short* wuhi = (unsigned short*)(ws + 67108864);    // 16 MB
    _Float16*       hhi  = (_Float16*)(ws + 83886080);          // 16 MB
    unsigned short* whh  = (unsigned short*)(ws + 117440512);   // 2 MB
    float*          bias4 = (float*)(ws + 119537664);           // 16 KB
    float*          logits = (float*)(ws + 33554432);           // 32 MB (free region)
    if (ws_size < (size_t)119554048) return;

    k_split_x<<<2048, 256, 0, stream>>>(input, hidden, xhi);
    k_trans_all<<<dim3(16, 16, 8), 256, 0, stream>>>(
        W_f, W_i, W_c, W_o, U_f, U_i, U_c, U_o, wuhi);
    k_trans_wh<<<dim3(16, 16), 256, 0, stream>>>(W_h, whh);
    k_pack_bias<<<16, 256, 0, stream>>>(b_f, b_i, b_c, b_o, bias4);

    // gates GEMM + fused LSTM epilogue: M=8192, N'=4096, K=2048, 2048 blocks
    k_gate_gemm<<<dim3(32, 64), 256, 0, stream>>>(
        (const char*)xhi, (const char*)wuhi, bias4, cell, out, hhi);

    // logits GEMM: M=8192, N=1024, K=1024 (single-product)
    k_gemm128<<<dim3(8, 64), 256, 0, stream>>>(
        (const char*)hhi, (const char*)whh, b_h, logits);

    k_logsoftmax<<<8192, 256, 0, stream>>>(logits, out);
}